// Round 5
// baseline (211.560 us; speedup 1.0000x reference)
//
#include <hip/hip_runtime.h>
#include <hip/hip_bf16.h>
#include <math.h>

#define BB 4
#define CC 256
#define DKK 32
#define NN 4096
// 1/sqrt(32) * log2(e) — folded into q at QKV epilogue; attention uses exp2.
#define QSCALE 0.2550181864060454f

typedef __attribute__((ext_vector_type(8))) __bf16 bf16x8;
typedef __attribute__((ext_vector_type(4))) __bf16 bf16x4;
typedef __attribute__((ext_vector_type(4))) float f32x4;

// ---------------------------------------------------------------------------
// Kernel 0: W fp32 -> bf16, rows [Wq(32); Wk(32); Wv(256)] = Wb[320][256]
// ---------------------------------------------------------------------------
__global__ __launch_bounds__(256) void wconv_kernel(
    const float* __restrict__ Wq, const float* __restrict__ Wk,
    const float* __restrict__ Wv, __bf16* __restrict__ Wb)
{
    int i = (blockIdx.x * 256 + threadIdx.x) * 4;   // 80 blocks
    int row = i >> 8, col = i & 255;
    const float* src;
    if (row < 32)      src = &Wq[row * 256 + col];
    else if (row < 64) src = &Wk[(row - 32) * 256 + col];
    else               src = &Wv[(row - 64) * 256 + col];
    float4 v = *(const float4*)src;
    Wb[i]     = (__bf16)v.x;
    Wb[i + 1] = (__bf16)v.y;
    Wb[i + 2] = (__bf16)v.z;
    Wb[i + 3] = (__bf16)v.w;
}

// ---------------------------------------------------------------------------
// Kernel 0b: transpose x (B,C,N) fp32 -> xT (B,N,C) bf16.
// ---------------------------------------------------------------------------
__global__ __launch_bounds__(256) void xtrans_kernel(
    const float* __restrict__ x, __bf16* __restrict__ xT)
{
    __shared__ float xs[64][68];
    const int tid = threadIdx.x;
    const int n0 = blockIdx.x * 64;
    const int c0 = blockIdx.y * 64;
    const int b  = blockIdx.z;
#pragma unroll
    for (int p = 0; p < 4; p++) {
        int cc = p * 16 + (tid >> 4);
        int nf = (tid & 15) * 4;
        float4 v = *(const float4*)&x[((size_t)(b * CC + c0 + cc)) * NN + n0 + nf];
        xs[cc][nf] = v.x; xs[cc][nf + 1] = v.y; xs[cc][nf + 2] = v.z; xs[cc][nf + 3] = v.w;
    }
    __syncthreads();
    int n = tid >> 2, cs = (tid & 3) * 16;
    bf16x8 lo, hi;
#pragma unroll
    for (int j = 0; j < 8; j++) {
        lo[j] = (__bf16)xs[cs + j][n];
        hi[j] = (__bf16)xs[cs + 8 + j][n];
    }
    size_t base = ((size_t)(b * NN + n0 + n)) * CC + c0 + cs;
    *(bf16x8*)&xT[base]     = lo;
    *(bf16x8*)&xT[base + 8] = hi;
}

// ---------------------------------------------------------------------------
// Kernel 1: QKV projection — MFMA GEMM, register-bounded depth-1 prefetch
// (no giant unroll-hoist -> no scratch spills). Block: 32 n x 320 o; wave w
// -> o 80w..80w+79. Grid 128 x B = 512 blocks (2/CU).
// ---------------------------------------------------------------------------
__global__ __launch_bounds__(256) void qkv_kernel(
    const __bf16* __restrict__ xT, const __bf16* __restrict__ Wb,
    const float* __restrict__ bq, const float* __restrict__ bk,
    const float* __restrict__ bv,
    __bf16* __restrict__ qws, __bf16* __restrict__ kws, __bf16* __restrict__ vws)
{
    __shared__ float scr[64][33];

    const int tid = threadIdx.x;
    const int w   = tid >> 6;
    const int l   = tid & 63;
    const int l15 = l & 15;
    const int lq  = l >> 4;
    const int n0  = blockIdx.x * 32;
    const int b   = blockIdx.y;

    const __bf16* xbase = xT + ((size_t)b * NN + n0 + l15) * CC + lq * 8;
    const __bf16* wbase = Wb + (size_t)(80 * w + l15) * CC + lq * 8;

    const f32x4 zf = {0.f, 0.f, 0.f, 0.f};
    f32x4 acc[5][2];
#pragma unroll
    for (int i = 0; i < 5; i++)
#pragma unroll
        for (int j = 0; j < 2; j++) acc[i][j] = zf;

    bf16x8 bcur[2], acur[5], bnxt[2], anxt[5];
#pragma unroll
    for (int nt = 0; nt < 2; nt++) bcur[nt] = *(const bf16x8*)(xbase + nt * 16 * CC);
#pragma unroll
    for (int ot = 0; ot < 5; ot++) acur[ot] = *(const bf16x8*)(wbase + ot * 16 * CC);

#pragma unroll
    for (int ks = 0; ks < 8; ks++) {
        if (ks < 7) {
#pragma unroll
            for (int nt = 0; nt < 2; nt++)
                bnxt[nt] = *(const bf16x8*)(xbase + nt * 16 * CC + (ks + 1) * 32);
#pragma unroll
            for (int ot = 0; ot < 5; ot++)
                anxt[ot] = *(const bf16x8*)(wbase + ot * 16 * CC + (ks + 1) * 32);
        }
#pragma unroll
        for (int ot = 0; ot < 5; ot++)
#pragma unroll
            for (int nt = 0; nt < 2; nt++)
                acc[ot][nt] = __builtin_amdgcn_mfma_f32_16x16x32_bf16(acur[ot], bcur[nt], acc[ot][nt], 0, 0, 0);
        if (ks < 7) {
#pragma unroll
            for (int nt = 0; nt < 2; nt++) bcur[nt] = bnxt[nt];
#pragma unroll
            for (int ot = 0; ot < 5; ot++) acur[ot] = anxt[ot];
        }
    }

    // epilogue: D row o = 80w + ot*16 + lq*4 + r, col n = nt*16 + l15
#pragma unroll
    for (int ot = 0; ot < 5; ot++) {
        int ob = 80 * w + ot * 16;
#pragma unroll
        for (int nt = 0; nt < 2; nt++) {
#pragma unroll
            for (int r = 0; r < 4; r++) {
                int o = ob + lq * 4 + r;
                int n = nt * 16 + l15;
                float val = acc[ot][nt][r];
                if (ob >= 64) {
                    int c = o - 64;
                    vws[((size_t)b * CC + c) * NN + n0 + n] = (__bf16)(val + bv[c]);
                } else if (ob < 32) {
                    scr[o][n] = (val + bq[o]) * QSCALE;
                } else {
                    scr[o][n] = val + bk[o - 32];
                }
            }
        }
    }
    __syncthreads();
    {
        int n  = tid >> 3;            // 0..31
        int d0 = (tid & 7) * 4;       // 0..28
        bf16x4 qv, kv;
#pragma unroll
        for (int j = 0; j < 4; j++) {
            qv[j] = (__bf16)scr[d0 + j][n];
            kv[j] = (__bf16)scr[32 + d0 + j][n];
        }
        size_t base = ((size_t)b * NN + n0 + n) * DKK + d0;
        *(bf16x4*)&qws[base] = qv;
        *(bf16x4*)&kws[base] = kv;
    }
}

// ---------------------------------------------------------------------------
// Kernel 2: flash attention, pipelined K-loop.
// Block: 64 m (grid 256, 1/CU), 4 waves. Wave w: KQ^T for n-strip (w&1)*16,
// m-half (w>>1); PV for c-quarter 64w..64w+63 over all 64 m.
// V: DIRECT global->reg double-buffer (c-split => no LDS multicast value).
// P: LDS double-buffer; iteration ic runs PV(ic) interleaved with
// KQ(ic+1)+exp into the other P buffer; ONE lgkm-only barrier per chunk.
// ---------------------------------------------------------------------------
#define PST 40   // LDS row stride (bf16): 80B rows -> 2-way banks (free), 16B-aligned

__global__ __launch_bounds__(256, 1) void attn_kernel(
    const __bf16* __restrict__ qb, const __bf16* __restrict__ kb,
    const __bf16* __restrict__ vb, const float* __restrict__ x,
    float* __restrict__ out)
{
    __shared__ __align__(16) __bf16 pbuf[2][64 * PST];   // 10240 B
    __shared__ float Ls[4][32];

    const int tid = threadIdx.x;
    const int w   = tid >> 6;
    const int l   = tid & 63;
    const int l15 = l & 15;
    const int lq  = l >> 4;

    // XCD swizzle: batch pinned to an XCD pair -> K/V/Q stay L2-resident
    const int beta = blockIdx.x;
    const int b    = (beta >> 1) & 3;
    const int mt   = ((beta >> 3) << 1) | (beta & 1);   // 0..63
    const int m0   = mt * 64;

    const __bf16* qbb = qb + (size_t)b * NN * DKK;
    const __bf16* kbb = kb + (size_t)b * NN * DKK;
    const __bf16* vbb = vb + (size_t)b * CC * NN;

    bf16x8 qa[4];
#pragma unroll
    for (int af = 0; af < 4; af++)
        qa[af] = *(const bf16x8*)(qbb + (size_t)(m0 + af * 16 + l15) * DKK + lq * 8);

    const int nsub = (w & 1) * 16;
    const int mh   = w >> 1;

    const __bf16* kptr = kbb + (size_t)(nsub + l15) * DKK + lq * 8;    // + nc*DKK
    const __bf16* vptr = vbb + (size_t)(w * 64 + l15) * NN + lq * 8;   // + ct*16*NN + nc

    const f32x4 zf = {0.f, 0.f, 0.f, 0.f};
    f32x4 acc[4][4];
#pragma unroll
    for (int i = 0; i < 4; i++)
#pragma unroll
        for (int j = 0; j < 4; j++) acc[i][j] = zf;
    float lacc0 = 0.f, lacc1 = 0.f;

    // ---- prologue: P(0), prefetch k(1)/V(0)/V(1) ----
    bf16x8 kf_u = *(const bf16x8*)kptr;
    bf16x8 vcur[4], vnxt[4];
#pragma unroll
    for (int ct = 0; ct < 4; ct++)
        vcur[ct] = *(const bf16x8*)(vptr + (size_t)ct * 16 * NN);
    {
        f32x4 e0 = __builtin_amdgcn_mfma_f32_16x16x32_bf16(kf_u, qa[2 * mh],     zf, 0, 0, 0);
        f32x4 e1 = __builtin_amdgcn_mfma_f32_16x16x32_bf16(kf_u, qa[2 * mh + 1], zf, 0, 0, 0);
        bf16x4 p0, p1;
#pragma unroll
        for (int r = 0; r < 4; r++) {
            float ev0 = __builtin_exp2f(e0[r]); lacc0 += ev0; p0[r] = (__bf16)ev0;
            float ev1 = __builtin_exp2f(e1[r]); lacc1 += ev1; p1[r] = (__bf16)ev1;
        }
        *(bf16x4*)&pbuf[0][((2 * mh)     * 16 + l15) * PST + nsub + lq * 4] = p0;
        *(bf16x4*)&pbuf[0][((2 * mh + 1) * 16 + l15) * PST + nsub + lq * 4] = p1;
    }
    kf_u = *(const bf16x8*)(kptr + (size_t)32 * DKK);
#pragma unroll
    for (int ct = 0; ct < 4; ct++)
        vnxt[ct] = *(const bf16x8*)(vptr + (size_t)ct * 16 * NN + 32);
    asm volatile("s_waitcnt lgkmcnt(0)\n\ts_barrier" ::: "memory");

#pragma unroll 2
    for (int ic = 0; ic < 128; ic++) {
        const int cur = ic & 1;

        // P frags for PV(ic) (published by barrier at end of prev iter)
        bf16x8 pf[4];
#pragma unroll
        for (int af = 0; af < 4; af++)
            pf[af] = *(const bf16x8*)&pbuf[cur][(af * 16 + l15) * PST + lq * 8];

        // KQ(ic+1) + exp into the other buffer (overlaps PV's MFMAs)
        if (ic < 127) {
            f32x4 e0 = __builtin_amdgcn_mfma_f32_16x16x32_bf16(kf_u, qa[2 * mh],     zf, 0, 0, 0);
            f32x4 e1 = __builtin_amdgcn_mfma_f32_16x16x32_bf16(kf_u, qa[2 * mh + 1], zf, 0, 0, 0);
            bf16x4 p0, p1;
#pragma unroll
            for (int r = 0; r < 4; r++) {
                float ev0 = __builtin_exp2f(e0[r]); lacc0 += ev0; p0[r] = (__bf16)ev0;
                float ev1 = __builtin_exp2f(e1[r]); lacc1 += ev1; p1[r] = (__bf16)ev1;
            }
            *(bf16x4*)&pbuf[cur ^ 1][((2 * mh)     * 16 + l15) * PST + nsub + lq * 4] = p0;
            *(bf16x4*)&pbuf[cur ^ 1][((2 * mh + 1) * 16 + l15) * PST + nsub + lq * 4] = p1;
        }

        // PV(ic): O[c][m] += V[c][n] P[m][n]
#pragma unroll
        for (int ct = 0; ct < 4; ct++)
#pragma unroll
            for (int af = 0; af < 4; af++)
                acc[af][ct] = __builtin_amdgcn_mfma_f32_16x16x32_bf16(vcur[ct], pf[af], acc[af][ct], 0, 0, 0);

        // rotate V regs; prefetch chunk ic+2
        if (ic < 127) {
#pragma unroll
            for (int ct = 0; ct < 4; ct++) vcur[ct] = vnxt[ct];
            if (ic < 126) {
#pragma unroll
                for (int ct = 0; ct < 4; ct++)
                    vnxt[ct] = *(const bf16x8*)(vptr + (size_t)ct * 16 * NN + (ic + 2) * 32);
                kf_u = *(const bf16x8*)(kptr + (size_t)(ic + 2) * 32 * DKK);
            }
        }
        asm volatile("s_waitcnt lgkmcnt(0)\n\ts_barrier" ::: "memory");
    }

    // ---- l: per-lane partials -> per-m sums ----
#pragma unroll
    for (int msk = 16; msk <= 32; msk <<= 1) {
        lacc0 += __shfl_xor(lacc0, msk, 64);
        lacc1 += __shfl_xor(lacc1, msk, 64);
    }
    if (l < 16) {
        Ls[w][l]      = lacc0;
        Ls[w][16 + l] = lacc1;
    }
    __syncthreads();

    // ---- epilogue: normalize (per-lane scalar), residual, store ----
#pragma unroll
    for (int af = 0; af < 4; af++) {
        int wpair = (af >> 1) * 2;
        float s = Ls[wpair][(af & 1) * 16 + l15] + Ls[wpair + 1][(af & 1) * 16 + l15];
        float rv = 1.0f / s;
#pragma unroll
        for (int ct = 0; ct < 4; ct++) {
#pragma unroll
            for (int r = 0; r < 4; r++) {
                int c = w * 64 + ct * 16 + lq * 4 + r;
                size_t gi = ((size_t)(b * CC + c)) * NN + m0 + af * 16 + l15;
                out[gi] = acc[af][ct][r] * rv + x[gi];
            }
        }
    }
}

extern "C" void kernel_launch(void* const* d_in, const int* in_sizes, int n_in,
                              void* d_out, int out_size, void* d_ws, size_t ws_size,
                              hipStream_t stream) {
    const float* x  = (const float*)d_in[0];
    const float* Wq = (const float*)d_in[1];
    const float* bq = (const float*)d_in[2];
    const float* Wk = (const float*)d_in[3];
    const float* bk = (const float*)d_in[4];
    const float* Wv = (const float*)d_in[5];
    const float* bv = (const float*)d_in[6];
    float* out = (float*)d_out;

    __bf16* qws = (__bf16*)d_ws;                       // B*N*32
    __bf16* kws = qws + (size_t)BB * NN * DKK;         // B*N*32
    __bf16* vws = kws + (size_t)BB * NN * DKK;         // B*C*N
    __bf16* Wb  = vws + (size_t)BB * CC * NN;          // 320*256
    __bf16* xT  = Wb  + (size_t)320 * CC;              // B*N*C

    wconv_kernel <<<dim3(80), 256, 0, stream>>>(Wq, Wk, Wv, Wb);
    xtrans_kernel<<<dim3(64, 4, BB), 256, 0, stream>>>(x, xT);
    qkv_kernel   <<<dim3(128, BB), 256, 0, stream>>>(xT, Wb, bq, bk, bv, qws, kws, vws);
    attn_kernel  <<<dim3(256), 256, 0, stream>>>(qws, kws, vws, x, out);
}